// Round 1
// baseline (71.628 us; speedup 1.0000x reference)
//
#include <hip/hip_runtime.h>

// Problem constants (from reference setup_inputs)
constexpr int S_ = 16;
constexpr int B_ = 64;
constexpr int T_ = 640;
constexpr int D_ = 256;
constexpr int H_ = 64;           // distinct harmonics = D / NUM_CH

__device__ __forceinline__ float fractf_(float x) { return __builtin_amdgcn_fractf(x); }
// sin(2*pi*r), r must already be in [0,1)
__device__ __forceinline__ float sin2pi_(float r) { return __builtin_amdgcn_sinf(r); }

// out[s,b,d] = a_d * ( cos(phi_d) * S_h + sin(phi_d) * C_h ),  h = d>>2
//   S_h = sum_k sin(2*pi*(h+1)*f*(k*dt - tau)) * x_k
//   C_h = sum_k cos(...) * x_k
// Inner loop: Givens-rotation phase recurrence (no transcendentals),
// re-anchored per 160-sample wave slice from double-reduced phase.
__global__ __launch_bounds__(256, 4)
void sinenet_kernel(const float* __restrict__ x,
                    const float* __restrict__ nlf,
                    const float* __restrict__ tau,
                    const float* __restrict__ a,
                    const float* __restrict__ phi,
                    float* __restrict__ out)
{
    __shared__ __align__(16) float xs[T_];
    __shared__ float redS[4][H_];
    __shared__ float redC[4][H_];

    const int sb   = blockIdx.x;     // s*B + b
    const int tid  = threadIdx.x;
    const int w    = tid >> 6;       // wave id 0..3
    const int lane = tid & 63;       // harmonic h

    // ---- stage x[sb, :] into LDS (160 float4 = 640 floats) ----
    const float4* xg4 = reinterpret_cast<const float4*>(x + (size_t)sb * T_);
    if (tid < T_ / 4) reinterpret_cast<float4*>(xs)[tid] = xg4[tid];

    // ---- per-(s,b) scalars (double for exact mod-1 reduction) ----
    const double fd = exp((double)nlf[sb] * 0.373288 + 5.02654);  // fundamental freq
    const double g  = fd * (1.0 / 16000.0);                       // revs per sample (h=1)
    const double q  = fd * (double)tau[sb];                       // revs offset (h=1)

    const int kstart = w * 160;

    // ---- per-lane phase setup ----
    const double hp = (double)(lane + 1);
    double mu = hp * g;                 // revs/sample for this harmonic
    mu -= floor(mu);                    // exact: sin has period 1 in revs
    double r0 = mu * (double)kstart - hp * q;
    r0 -= floor(r0);                    // starting phase in [0,1) revs

    const float muf  = (float)mu;
    const float r0f  = (float)r0;
    const float sm   = sin2pi_(fractf_(muf));           // sin(step angle)
    const float cm   = sin2pi_(fractf_(muf + 0.25f));   // cos(step angle)
    float s          = sin2pi_(fractf_(r0f));           // sin(phase at kstart)
    float c          = sin2pi_(fractf_(r0f + 0.25f));   // cos(phase at kstart)

    float Ss = 0.0f, Cs = 0.0f;

    __syncthreads();

    // ---- main loop: 160 samples, 4 per iteration ----
    const float4* xl = reinterpret_cast<const float4*>(xs + kstart);
#pragma unroll 4
    for (int i = 0; i < 40; ++i) {
        const float4 xv = xl[i];

        Ss = fmaf(s, xv.x, Ss); Cs = fmaf(c, xv.x, Cs);
        { float ns = fmaf(s, cm, c * sm); c = fmaf(c, cm, -(s * sm)); s = ns; }

        Ss = fmaf(s, xv.y, Ss); Cs = fmaf(c, xv.y, Cs);
        { float ns = fmaf(s, cm, c * sm); c = fmaf(c, cm, -(s * sm)); s = ns; }

        Ss = fmaf(s, xv.z, Ss); Cs = fmaf(c, xv.z, Cs);
        { float ns = fmaf(s, cm, c * sm); c = fmaf(c, cm, -(s * sm)); s = ns; }

        Ss = fmaf(s, xv.w, Ss); Cs = fmaf(c, xv.w, Cs);
        { float ns = fmaf(s, cm, c * sm); c = fmaf(c, cm, -(s * sm)); s = ns; }
    }

    redS[w][lane] = Ss;
    redC[w][lane] = Cs;
    __syncthreads();

    // ---- epilogue: all 256 threads, one output d each ----
    const int d = tid;
    const int h = tid >> 2;
    const float Sh = redS[0][h] + redS[1][h] + redS[2][h] + redS[3][h];
    const float Ch = redC[0][h] + redC[1][h] + redC[2][h] + redC[3][h];

    const float av  = a[d];
    const float pr  = phi[d] * 0.15915494309189535f;    // phi in revs
    const float sp  = sin2pi_(fractf_(pr));
    const float cp  = sin2pi_(fractf_(pr + 0.25f));

    out[(size_t)sb * D_ + d] = av * fmaf(cp, Sh, sp * Ch);
}

extern "C" void kernel_launch(void* const* d_in, const int* in_sizes, int n_in,
                              void* d_out, int out_size, void* d_ws, size_t ws_size,
                              hipStream_t stream)
{
    const float* x   = (const float*)d_in[0];
    const float* nlf = (const float*)d_in[1];
    const float* tau = (const float*)d_in[2];
    const float* a   = (const float*)d_in[3];
    const float* phi = (const float*)d_in[4];
    // d_in[5] = i_2pi (implied by d), d_in[6] = k_T (implied by k) — not needed
    float* out = (float*)d_out;

    dim3 grid(S_ * B_);
    dim3 block(256);
    hipLaunchKernelGGL(sinenet_kernel, grid, block, 0, stream,
                       x, nlf, tau, a, phi, out);
}

// Round 2
// 71.455 us; speedup vs baseline: 1.0024x; 1.0024x over previous
//
#include <hip/hip_runtime.h>

// Problem constants (from reference setup_inputs)
constexpr int S_  = 16;
constexpr int B_  = 64;
constexpr int T_  = 640;
constexpr int D_  = 256;
constexpr int H_  = 64;          // distinct harmonics = D / NUM_CH
constexpr int SB_ = S_ * B_;     // 1024 independent (s,b) problems

__device__ __forceinline__ float fractf_(float x) { return __builtin_amdgcn_fractf(x); }
// sin(2*pi*r); r must already be in [0,1)
__device__ __forceinline__ float sin2pi_(float r) { return __builtin_amdgcn_sinf(r); }

struct GQ { double g, q; };      // g = f/16000 (revs/sample, h=1), q = f*tau (revs, h=1)

// ---- tiny precompute: per-(s,b) fp64 exp + per-d phi decomposition ----
__global__ void sinenet_pre(const float* __restrict__ nlf,
                            const float* __restrict__ tau,
                            const float* __restrict__ a,
                            const float* __restrict__ phi,
                            GQ* __restrict__ gq,
                            float* __restrict__ ca,
                            float* __restrict__ sa)
{
    const int idx = blockIdx.x * 256 + threadIdx.x;
    if (idx < SB_) {
        const double fd = exp((double)nlf[idx] * 0.373288 + 5.02654);
        GQ v;
        v.g = fd * (1.0 / 16000.0);
        v.q = fd * (double)tau[idx];
        gq[idx] = v;
    } else if (idx < SB_ + D_) {
        const int d  = idx - SB_;
        const float av = a[d];
        const float pr = phi[d] * 0.15915494309189535f;   // phi in revolutions
        sa[d] = av * sin2pi_(fractf_(pr));                // a*sin(phi)
        ca[d] = av * sin2pi_(fractf_(pr + 0.25f));        // a*cos(phi)
    }
}

// out[s,b,d] = ca_d * S_h + sa_d * C_h,  h = d>>2
//   S_h = sum_k sin(2*pi*(h+1)*f*(k*dt - tau)) * x_k ; C_h analog with cos.
// Inner loop: Givens-rotation phase recurrence, two interleaved 80-sample
// streams per lane for ILP; anchors double-reduced mod 1.
__global__ __launch_bounds__(256, 4)
void sinenet_main(const float* __restrict__ x,
                  const GQ* __restrict__ gq,
                  const float* __restrict__ ca,
                  const float* __restrict__ sa,
                  float* __restrict__ out)
{
    __shared__ __align__(16) float xs[T_];
    __shared__ float redS[4][H_];
    __shared__ float redC[4][H_];

    const int sb   = blockIdx.x;
    const int tid  = threadIdx.x;
    const int w    = tid >> 6;       // wave id 0..3
    const int lane = tid & 63;       // harmonic h

    // stage x[sb,:] into LDS (160 float4)
    const float4* xg4 = reinterpret_cast<const float4*>(x + (size_t)sb * T_);
    if (tid < T_ / 4) reinterpret_cast<float4*>(xs)[tid] = xg4[tid];

    // per-(s,b) scalars (uniform -> scalar loads)
    const double g = gq[sb].g;
    const double q = gq[sb].q;

    const int kA = w * 160;          // stream A start
    const int kB = kA + 80;          // stream B start

    // per-lane phase anchors (exact mod-1 in fp64)
    const double hp = (double)(lane + 1);
    double mu = hp * g;  mu -= floor(mu);
    double rA = mu * (double)kA - hp * q;  rA -= floor(rA);
    double rB = rA + mu * 80.0;            rB -= floor(rB);

    const float muf = (float)mu;
    const float sm  = sin2pi_(fractf_(muf));          // sin(step)
    const float cm  = sin2pi_(fractf_(muf + 0.25f));  // cos(step)
    float sA = sin2pi_(fractf_((float)rA));
    float cA = sin2pi_(fractf_((float)rA + 0.25f));
    float sB = sin2pi_(fractf_((float)rB));
    float cB = sin2pi_(fractf_((float)rB + 0.25f));

    float SsA = 0.0f, CsA = 0.0f, SsB = 0.0f, CsB = 0.0f;

    __syncthreads();

    const float4* xa = reinterpret_cast<const float4*>(xs + kA);
    const float4* xb = reinterpret_cast<const float4*>(xs + kB);

#define STEP(sv, cv, Sacc, Cacc, xval)                                  \
    Sacc = fmaf(sv, xval, Sacc); Cacc = fmaf(cv, xval, Cacc);           \
    { float ns_ = fmaf(sv, cm, cv * sm);                                \
      cv = fmaf(cv, cm, -(sv * sm)); sv = ns_; }

#pragma unroll 4
    for (int i = 0; i < 20; ++i) {
        const float4 va = xa[i];
        const float4 vb = xb[i];
        STEP(sA, cA, SsA, CsA, va.x)  STEP(sB, cB, SsB, CsB, vb.x)
        STEP(sA, cA, SsA, CsA, va.y)  STEP(sB, cB, SsB, CsB, vb.y)
        STEP(sA, cA, SsA, CsA, va.z)  STEP(sB, cB, SsB, CsB, vb.z)
        STEP(sA, cA, SsA, CsA, va.w)  STEP(sB, cB, SsB, CsB, vb.w)
    }
#undef STEP

    redS[w][lane] = SsA + SsB;
    redC[w][lane] = CsA + CsB;
    __syncthreads();

    // epilogue: one output d per thread, coalesced
    const int d = tid;
    const int h = tid >> 2;
    const float Sh = redS[0][h] + redS[1][h] + redS[2][h] + redS[3][h];
    const float Ch = redC[0][h] + redC[1][h] + redC[2][h] + redC[3][h];
    out[(size_t)sb * D_ + d] = fmaf(ca[d], Sh, sa[d] * Ch);
}

extern "C" void kernel_launch(void* const* d_in, const int* in_sizes, int n_in,
                              void* d_out, int out_size, void* d_ws, size_t ws_size,
                              hipStream_t stream)
{
    const float* x   = (const float*)d_in[0];
    const float* nlf = (const float*)d_in[1];
    const float* tau = (const float*)d_in[2];
    const float* a   = (const float*)d_in[3];
    const float* phi = (const float*)d_in[4];
    float* out = (float*)d_out;

    // workspace layout: gq[1024] (16 KB) | ca[256] | sa[256]
    GQ*    gq = (GQ*)d_ws;
    float* ca = (float*)((char*)d_ws + SB_ * sizeof(GQ));
    float* sa = ca + D_;

    hipLaunchKernelGGL(sinenet_pre, dim3((SB_ + D_ + 255) / 256), dim3(256), 0, stream,
                       nlf, tau, a, phi, gq, ca, sa);
    hipLaunchKernelGGL(sinenet_main, dim3(SB_), dim3(256), 0, stream,
                       x, gq, ca, sa, out);
}